// Round 1
// baseline (15403.241 us; speedup 1.0000x reference)
//
#include <hip/hip_runtime.h>
#include <hip/hip_bf16.h>
#include <cstdint>

// ---------------------------------------------------------------------------
// Model_2886218023415: GAT/GraphConv graph stage -> BiLSTM+attn x2 -> FC
// Round 1: full fp32 implementation, 3 kernels, sequence stage fused per-sample.
// ---------------------------------------------------------------------------

#define NCH 7
#define SEQ 10
#define NN  10
#define BS  132   // padded row stride for [10][128] sequence buffers (16B aligned, bank-skewed)

// Fixed graph (20 directed edges), see reference _edges()
__constant__ int c_src[20] = {0,7,1,7,2,7,3,7,4,8,5,8,6,8,7,8,7,9,8,9};
__constant__ int c_dst[20] = {7,0,7,1,7,2,7,3,8,4,8,5,8,6,8,7,9,7,9,8};
// Incoming-edge lists per dst WITH self-loops (edge id 20+n is self-loop of node n)
__constant__ int c_in_start[11] = {0,2,4,6,8,10,12,14,21,27,30};
__constant__ int c_in_edge[30] = {1,20, 3,21, 5,22, 7,23, 9,24, 11,25, 13,26,
                                  0,2,4,6,15,17,27,
                                  8,10,12,14,19,28,
                                  16,18,29};
// Incoming source-node lists per dst WITHOUT self-loops (GraphConv)
__constant__ int c_gin_start[11] = {0,1,2,3,4,5,6,7,13,18,20};
__constant__ int c_gin_src[20] = {7,7,7,7,8,8,8, 0,1,2,3,8,9, 4,5,6,7,9, 7,8};

__device__ __forceinline__ float fsig(float x){ return 1.f/(1.f + __expf(-x)); }
__device__ __forceinline__ float ftanh(float x){ return 1.f - 2.f/(__expf(2.f*x) + 1.f); }

// ---------------------------------------------------------------------------
// Kernel 1: graph stage. One wave (64 threads) per sample. Emits xseq [B,10,21].
// ---------------------------------------------------------------------------
__global__ __launch_bounds__(64) void graph_kernel(
    const float* __restrict__ M,       // [B,7,10]
    const float* __restrict__ W1,      // [10,128]  (f, h*32+c)
    const float* __restrict__ as1,     // [128]
    const float* __restrict__ ad1,     // [128]
    const float* __restrict__ b1,      // [128]
    const float* __restrict__ W2,      // [128,10]
    const float* __restrict__ as2,     // [10]
    const float* __restrict__ ad2,     // [10]
    const float* __restrict__ b2,      // [10]
    const float* __restrict__ gWrel1,  // [10,32]
    const float* __restrict__ gWroot1, // [10,32]
    const float* __restrict__ gb1,     // [32]
    const float* __restrict__ gWrel2,  // [32,10]
    const float* __restrict__ gWroot2, // [32,10]
    const float* __restrict__ gb2,     // [10]
    float* __restrict__ xseq)          // [B,10,21]
{
    const int b = blockIdx.x;
    const int tid = threadIdx.x;

    __shared__ float s_nf[10][10];
    __shared__ float s_xh[10][129];
    __shared__ float s_h[10][129];
    __shared__ float s_as[10][4], s_ad[10][4];
    __shared__ float s_al[30][4];
    __shared__ float s_xh2[10][10];
    __shared__ float s_as2[10], s_ad2[10];
    __shared__ float s_al2[30];
    __shared__ float s_mp[10][10];
    __shared__ float s_agg[10][10];
    __shared__ float s_g[10][33];
    __shared__ float s_gagg[10][33];
    __shared__ float s_bf[10][10];

    // node features: M channels 0..6, zero-pad nodes 7..9
    const float* Mb = M + (size_t)b * 70;
    for (int i = tid; i < 100; i += 64) {
        int n = i / 10, f = i - n * 10;
        s_nf[n][f] = (n < 7) ? Mb[n * 10 + f] : 0.f;
    }
    // hoist W1 columns for this lane's two hc slots
    float wA[10], wB[10];
    #pragma unroll
    for (int f = 0; f < 10; f++) { wA[f] = W1[f*128 + tid]; wB[f] = W1[f*128 + tid + 64]; }
    __syncthreads();

    // GAT1: xh = nf @ W1   [10 nodes][128]
    for (int n = 0; n < 10; n++) {
        float a0 = 0.f, a1 = 0.f;
        #pragma unroll
        for (int f = 0; f < 10; f++) { float x = s_nf[n][f]; a0 += x*wA[f]; a1 += x*wB[f]; }
        s_xh[n][tid] = a0; s_xh[n][tid + 64] = a1;
    }
    __syncthreads();
    // attention scalars per (node, head)
    if (tid < 40) {
        int n = tid >> 2, h = tid & 3;
        float va = 0.f, vd = 0.f;
        #pragma unroll
        for (int c = 0; c < 32; c++) {
            float x = s_xh[n][h*32 + c];
            va += x * as1[h*32 + c];
            vd += x * ad1[h*32 + c];
        }
        s_as[n][h] = va; s_ad[n][h] = vd;
    }
    __syncthreads();
    // edge logits (leaky_relu 0.2), 30 edges x 4 heads
    for (int i = tid; i < 120; i += 64) {
        int e = i >> 2, h = i & 3;
        int sn = (e < 20) ? c_src[e] : e - 20;
        int dn = (e < 20) ? c_dst[e] : e - 20;
        float v = s_as[sn][h] + s_ad[dn][h];
        s_al[e][h] = (v >= 0.f) ? v : 0.2f * v;
    }
    __syncthreads();
    // softmax over incoming edges per (dst, head)
    if (tid < 40) {
        int n = tid >> 2, h = tid & 3;
        int st = c_in_start[n], en = c_in_start[n+1];
        float m = -1e30f;
        for (int j = st; j < en; j++) m = fmaxf(m, s_al[c_in_edge[j]][h]);
        float den = 0.f;
        for (int j = st; j < en; j++) den += __expf(s_al[c_in_edge[j]][h] - m);
        float inv = 1.f / den;
        for (int j = st; j < en; j++) {
            int e = c_in_edge[j];
            s_al[e][h] = __expf(s_al[e][h] - m) * inv;
        }
    }
    __syncthreads();
    // aggregate + bias + relu -> h [10][128]
    for (int i = tid; i < 1280; i += 64) {
        int n = i >> 7, hc = i & 127, h = hc >> 5;
        int st = c_in_start[n], en = c_in_start[n+1];
        float o = b1[hc];
        for (int j = st; j < en; j++) {
            int e = c_in_edge[j];
            int sn = (e < 20) ? c_src[e] : e - 20;
            o += s_al[e][h] * s_xh[sn][hc];
        }
        s_h[n][hc] = fmaxf(o, 0.f);
    }
    __syncthreads();
    // GAT2: xh2 = h @ W2  [10][10]
    for (int i = tid; i < 100; i += 64) {
        int n = i / 10, c = i - (i / 10) * 10;
        float a = 0.f;
        #pragma unroll 16
        for (int f = 0; f < 128; f++) a += s_h[n][f] * W2[f*10 + c];
        s_xh2[n][c] = a;
    }
    __syncthreads();
    if (tid < 20) {
        int n = (tid < 10) ? tid : tid - 10;
        const float* av = (tid < 10) ? as2 : ad2;
        float v = 0.f;
        #pragma unroll
        for (int c = 0; c < 10; c++) v += s_xh2[n][c] * av[c];
        if (tid < 10) s_as2[n] = v; else s_ad2[n] = v;
    }
    __syncthreads();
    if (tid < 30) {
        int e = tid;
        int sn = (e < 20) ? c_src[e] : e - 20;
        int dn = (e < 20) ? c_dst[e] : e - 20;
        float v = s_as2[sn] + s_ad2[dn];
        s_al2[e] = (v >= 0.f) ? v : 0.2f * v;
    }
    __syncthreads();
    if (tid < 10) {
        int st = c_in_start[tid], en = c_in_start[tid+1];
        float m = -1e30f;
        for (int j = st; j < en; j++) m = fmaxf(m, s_al2[c_in_edge[j]]);
        float den = 0.f;
        for (int j = st; j < en; j++) den += __expf(s_al2[c_in_edge[j]] - m);
        float inv = 1.f / den;
        for (int j = st; j < en; j++) s_al2[c_in_edge[j]] = __expf(s_al2[c_in_edge[j]] - m) * inv;
    }
    __syncthreads();
    for (int i = tid; i < 100; i += 64) {
        int n = i / 10, c = i - (i / 10) * 10;
        int st = c_in_start[n], en = c_in_start[n+1];
        float o = b2[c];
        for (int j = st; j < en; j++) {
            int e = c_in_edge[j];
            int sn = (e < 20) ? c_src[e] : e - 20;
            o += s_al2[e] * s_xh2[sn][c];
        }
        s_mp[n][c] = o;   // no relu
    }
    __syncthreads();
    // GraphConv1: agg over incoming (no self loops)
    for (int i = tid; i < 100; i += 64) {
        int n = i / 10, f = i - (i / 10) * 10;
        int st = c_gin_start[n], en = c_gin_start[n+1];
        float a = 0.f;
        for (int j = st; j < en; j++) a += s_nf[c_gin_src[j]][f];
        s_agg[n][f] = a;
    }
    __syncthreads();
    for (int i = tid; i < 320; i += 64) {
        int n = i >> 5, c = i & 31;
        float v = gb1[c];
        #pragma unroll
        for (int f = 0; f < 10; f++)
            v += s_agg[n][f] * gWrel1[f*32 + c] + s_nf[n][f] * gWroot1[f*32 + c];
        s_g[n][c] = fmaxf(v, 0.f);
    }
    __syncthreads();
    // GraphConv2
    for (int i = tid; i < 320; i += 64) {
        int n = i >> 5, c = i & 31;
        int st = c_gin_start[n], en = c_gin_start[n+1];
        float a = 0.f;
        for (int j = st; j < en; j++) a += s_g[c_gin_src[j]][c];
        s_gagg[n][c] = a;
    }
    __syncthreads();
    for (int i = tid; i < 100; i += 64) {
        int n = i / 10, c = i - (i / 10) * 10;
        float v = gb2[c];
        #pragma unroll
        for (int f = 0; f < 32; f++)
            v += s_gagg[n][f] * gWrel2[f*10 + c] + s_g[n][f] * gWroot2[f*10 + c];
        s_bf[n][c] = v;   // no relu
    }
    __syncthreads();
    // x_seq[t][k]: k<7 -> M[k][t]; k<14 -> Mp[k-7][t]; else bfeat[k-14][t]
    float* xo = xseq + (size_t)b * 210;
    for (int i = tid; i < 210; i += 64) {
        int t = i / 21, k = i - (i / 21) * 21;
        float v;
        if (k < 7)       v = s_nf[k][t];
        else if (k < 14) v = s_mp[k - 7][t];
        else             v = s_bf[k - 14][t];
        xo[i] = v;
    }
}

// ---------------------------------------------------------------------------
// LSTM direction inside a 256-thread block (one sample). Thread j owns gate j.
// ---------------------------------------------------------------------------
template<int IN, int STRIDE>
__device__ __forceinline__ void lstm_dir_block(
    const float* __restrict__ Wih, const float* __restrict__ Whh,
    const float* __restrict__ bias, const float* __restrict__ s_in,
    float* __restrict__ s_O, int col_off, int reverse,
    float* __restrict__ s_h, float* __restrict__ s_g,
    float* __restrict__ s_xw, int tid)
{
    // xw[t][j] = b[j] + sum_d x[t][d]*Wih[j][d]; each Wih row read exactly once
    float acc[10];
    {
        float bj = bias[tid];
        #pragma unroll
        for (int t = 0; t < 10; t++) acc[t] = bj;
    }
    const float* ir = Wih + (size_t)tid * IN;
    if constexpr (IN == 21) {
        for (int d = 0; d < 21; d++) {
            float w = ir[d];
            #pragma unroll
            for (int t = 0; t < 10; t++) acc[t] += w * s_in[t * STRIDE + d];
        }
    } else {
        for (int d = 0; d < IN; d += 4) {
            float4 wv = *(const float4*)(ir + d);
            #pragma unroll
            for (int t = 0; t < 10; t++) {
                float4 xv = *(const float4*)(s_in + t * STRIDE + d);
                acc[t] += wv.x*xv.x + wv.y*xv.y + wv.z*xv.z + wv.w*xv.w;
            }
        }
    }
    #pragma unroll
    for (int t = 0; t < 10; t++) s_xw[t * 256 + tid] = acc[t];

    // Whh row in registers
    float wh[64];
    const float* wr = Whh + (size_t)tid * 64;
    #pragma unroll
    for (int k = 0; k < 64; k += 4) {
        float4 wv = *(const float4*)(wr + k);
        wh[k] = wv.x; wh[k+1] = wv.y; wh[k+2] = wv.z; wh[k+3] = wv.w;
    }
    if (tid < 64) s_h[tid] = 0.f;
    float cst = 0.f;
    __syncthreads();

    for (int s = 0; s < 10; s++) {
        int t = reverse ? 9 - s : s;
        float g = s_xw[t * 256 + tid];
        #pragma unroll
        for (int k = 0; k < 64; k += 4) {
            float4 hv = *(const float4*)(s_h + k);   // broadcast ds_read_b128
            g += wh[k]*hv.x + wh[k+1]*hv.y + wh[k+2]*hv.z + wh[k+3]*hv.w;
        }
        s_g[tid] = g;
        __syncthreads();
        if (tid < 64) {
            float ig = fsig(s_g[tid]);
            float fg = fsig(s_g[64 + tid]);
            float gg = ftanh(s_g[128 + tid]);
            float og = fsig(s_g[192 + tid]);
            cst = fg * cst + ig * gg;
            float hv = og * ftanh(cst);
            s_h[tid] = hv;
            s_O[t * BS + col_off + tid] = hv;
        }
        __syncthreads();
    }
}

// self-attention: A = softmax(tanh(O@Wa.T+ba) @ O^T) @ O, all [10][128] (stride BS)
__device__ __forceinline__ void attn_block(
    const float* __restrict__ Wa, const float* __restrict__ ba,
    const float* __restrict__ O, float* __restrict__ A, float* __restrict__ Q,
    float* __restrict__ s_sc, int tid)
{
    #pragma unroll
    for (int p = 0; p < 5; p++) {
        int i = tid + p * 256; int t = i >> 7; int f = i & 127;
        const float* wr = Wa + f * 128;
        const float* orow = O + t * BS;
        float a = ba[f];
        #pragma unroll
        for (int k = 0; k < 128; k += 4) {
            float4 ov = *(const float4*)(orow + k);
            float4 wv = *(const float4*)(wr + k);
            a += ov.x*wv.x + ov.y*wv.y + ov.z*wv.z + ov.w*wv.w;
        }
        Q[t * BS + f] = ftanh(a);
    }
    __syncthreads();
    if (tid < 100) {
        int q = tid / 10, k = tid - q * 10;
        const float* qr = Q + q * BS;
        const float* orow = O + k * BS;
        float s = 0.f;
        #pragma unroll
        for (int f = 0; f < 128; f += 4) {
            float4 qv = *(const float4*)(qr + f);
            float4 ov = *(const float4*)(orow + f);
            s += qv.x*ov.x + qv.y*ov.y + qv.z*ov.z + qv.w*ov.w;
        }
        s_sc[tid] = s;
    }
    __syncthreads();
    if (tid < 10) {
        float m = -1e30f;
        #pragma unroll
        for (int k = 0; k < 10; k++) m = fmaxf(m, s_sc[tid*10 + k]);
        float den = 0.f;
        float e[10];
        #pragma unroll
        for (int k = 0; k < 10; k++) { e[k] = __expf(s_sc[tid*10 + k] - m); den += e[k]; }
        float inv = 1.f / den;
        #pragma unroll
        for (int k = 0; k < 10; k++) s_sc[tid*10 + k] = e[k] * inv;
    }
    __syncthreads();
    #pragma unroll
    for (int p = 0; p < 5; p++) {
        int i = tid + p * 256; int t = i >> 7; int f = i & 127;
        float a = 0.f;
        #pragma unroll
        for (int k = 0; k < 10; k++) a += s_sc[t*10 + k] * O[k * BS + f];
        A[t * BS + f] = a;
    }
    __syncthreads();
}

// ---------------------------------------------------------------------------
// Kernel 2: full sequence stage for one sample per block.
// ---------------------------------------------------------------------------
__global__ __launch_bounds__(256) void seq_kernel(
    const float* __restrict__ xseq,
    const float* __restrict__ W1f_ih, const float* __restrict__ W1f_hh, const float* __restrict__ b1f,
    const float* __restrict__ W1b_ih, const float* __restrict__ W1b_hh, const float* __restrict__ b1b,
    const float* __restrict__ W2f_ih, const float* __restrict__ W2f_hh, const float* __restrict__ b2f,
    const float* __restrict__ W2b_ih, const float* __restrict__ W2b_hh, const float* __restrict__ b2b,
    const float* __restrict__ Wa1, const float* __restrict__ ba1,
    const float* __restrict__ Wa2, const float* __restrict__ ba2,
    float* __restrict__ xbar)
{
    const int b = blockIdx.x, tid = threadIdx.x;
    __shared__ __align__(16) float s_x[10 * 24];
    __shared__ __align__(16) float s_B0[10 * BS];
    __shared__ __align__(16) float s_B1[10 * BS];
    __shared__ __align__(16) float s_B2[10 * BS];
    __shared__ __align__(16) float s_h[64];
    __shared__ float s_g[256];
    __shared__ float s_xw[10 * 256];
    __shared__ float s_sc[100];

    for (int i = tid; i < 210; i += 256) {
        int t = i / 21, k = i - (i / 21) * 21;
        s_x[t * 24 + k] = xseq[(size_t)b * 210 + i];
    }
    __syncthreads();

    lstm_dir_block<21, 24>(W1f_ih, W1f_hh, b1f, s_x, s_B0, 0,  0, s_h, s_g, s_xw, tid);
    lstm_dir_block<21, 24>(W1b_ih, W1b_hh, b1b, s_x, s_B0, 64, 1, s_h, s_g, s_xw, tid);
    attn_block(Wa1, ba1, s_B0, s_B1, s_B2, s_sc, tid);
    lstm_dir_block<128, BS>(W2f_ih, W2f_hh, b2f, s_B1, s_B0, 0,  0, s_h, s_g, s_xw, tid);
    lstm_dir_block<128, BS>(W2b_ih, W2b_hh, b2b, s_B1, s_B0, 64, 1, s_h, s_g, s_xw, tid);
    attn_block(Wa2, ba2, s_B0, s_B2, s_B1, s_sc, tid);

    if (tid < 128) {
        float a = 0.f;
        #pragma unroll
        for (int t = 0; t < 10; t++) a += s_B2[t * BS + tid];
        xbar[(size_t)b * 128 + tid] = a * 0.1f;
    }
}

// ---------------------------------------------------------------------------
// Kernel 3: FC  out[b][u] = xbar[b] . W[u] + bias[u]
// block: 256 thr = 16(tx:user) x 16(ty:sample); tile 64 users x 64 samples
// ---------------------------------------------------------------------------
__global__ __launch_bounds__(256) void fc_kernel(
    const float* __restrict__ xbar, const float* __restrict__ W,
    const float* __restrict__ fb, float* __restrict__ out, int B)
{
    __shared__ __align__(16) float s_xb[64 * BS];
    const int tid = threadIdx.x;
    const int b0 = blockIdx.y * 64;
    const int u0 = blockIdx.x * 64;

    for (int i = tid; i < 64 * 128; i += 256) {
        int s = i >> 7, k = i & 127;
        int bb = b0 + s;
        s_xb[s * BS + k] = (bb < B) ? xbar[(size_t)bb * 128 + k] : 0.f;
    }
    __syncthreads();

    const int tx = tid & 15, ty = tid >> 4;
    float acc[4][4] = {};
    for (int k = 0; k < 128; k += 4) {
        float4 wv[4], xv[4];
        #pragma unroll
        for (int j = 0; j < 4; j++) {
            int u = u0 + tx + 16 * j;
            int uc = (u < 1000) ? u : 999;
            wv[j] = *(const float4*)(W + (size_t)uc * 128 + k);
        }
        #pragma unroll
        for (int si = 0; si < 4; si++) {
            int s = ty + 16 * si;
            xv[si] = *(const float4*)(s_xb + s * BS + k);
        }
        #pragma unroll
        for (int j = 0; j < 4; j++)
            #pragma unroll
            for (int si = 0; si < 4; si++)
                acc[j][si] += wv[j].x*xv[si].x + wv[j].y*xv[si].y
                            + wv[j].z*xv[si].z + wv[j].w*xv[si].w;
    }
    #pragma unroll
    for (int j = 0; j < 4; j++) {
        int u = u0 + tx + 16 * j;
        if (u < 1000) {
            float bb = fb[u];
            #pragma unroll
            for (int si = 0; si < 4; si++) {
                int bsm = b0 + ty + 16 * si;
                if (bsm < B) out[(size_t)bsm * 1000 + u] = acc[j][si] + bb;
            }
        }
    }
}

// ---------------------------------------------------------------------------
extern "C" void kernel_launch(void* const* d_in, const int* in_sizes, int n_in,
                              void* d_out, int out_size, void* d_ws, size_t ws_size,
                              hipStream_t stream)
{
    const float* M       = (const float*)d_in[0];
    const float* ga1_W   = (const float*)d_in[1];
    const float* ga1_as  = (const float*)d_in[2];
    const float* ga1_ad  = (const float*)d_in[3];
    const float* ga1_b   = (const float*)d_in[4];
    const float* ga2_W   = (const float*)d_in[5];
    const float* ga2_as  = (const float*)d_in[6];
    const float* ga2_ad  = (const float*)d_in[7];
    const float* ga2_b   = (const float*)d_in[8];
    const float* gp1_Wrel  = (const float*)d_in[9];
    const float* gp1_Wroot = (const float*)d_in[10];
    const float* gp1_b     = (const float*)d_in[11];
    const float* gp2_Wrel  = (const float*)d_in[12];
    const float* gp2_Wroot = (const float*)d_in[13];
    const float* gp2_b     = (const float*)d_in[14];
    const float* l1f_Wih = (const float*)d_in[15];
    const float* l1f_Whh = (const float*)d_in[16];
    const float* l1f_b   = (const float*)d_in[17];
    const float* l1b_Wih = (const float*)d_in[18];
    const float* l1b_Whh = (const float*)d_in[19];
    const float* l1b_b   = (const float*)d_in[20];
    const float* l2f_Wih = (const float*)d_in[21];
    const float* l2f_Whh = (const float*)d_in[22];
    const float* l2f_b   = (const float*)d_in[23];
    const float* l2b_Wih = (const float*)d_in[24];
    const float* l2b_Whh = (const float*)d_in[25];
    const float* l2b_b   = (const float*)d_in[26];
    const float* a1_Wa   = (const float*)d_in[27];
    const float* a1_ba   = (const float*)d_in[28];
    const float* a2_Wa   = (const float*)d_in[29];
    const float* a2_ba   = (const float*)d_in[30];
    const float* fc_W    = (const float*)d_in[31];
    const float* fc_b    = (const float*)d_in[32];

    const int B = in_sizes[0] / 70;    // 32768

    float* xseq = (float*)d_ws;                                   // [B,10,21]
    float* xbar = (float*)((char*)d_ws + (size_t)B * 210 * 4);    // [B,128]

    graph_kernel<<<B, 64, 0, stream>>>(M,
        ga1_W, ga1_as, ga1_ad, ga1_b,
        ga2_W, ga2_as, ga2_ad, ga2_b,
        gp1_Wrel, gp1_Wroot, gp1_b,
        gp2_Wrel, gp2_Wroot, gp2_b,
        xseq);

    seq_kernel<<<B, 256, 0, stream>>>(xseq,
        l1f_Wih, l1f_Whh, l1f_b,
        l1b_Wih, l1b_Whh, l1b_b,
        l2f_Wih, l2f_Whh, l2f_b,
        l2b_Wih, l2b_Whh, l2b_b,
        a1_Wa, a1_ba, a2_Wa, a2_ba,
        xbar);

    dim3 fgrid((1000 + 63) / 64, (B + 63) / 64);
    fc_kernel<<<fgrid, 256, 0, stream>>>(xbar, fc_W, fc_b, (float*)d_out, B);
}

// Round 2
// 6375.882 us; speedup vs baseline: 2.4159x; 2.4159x over previous
//
#include <hip/hip_runtime.h>
#include <hip/hip_bf16.h>
#include <cstdint>

// ---------------------------------------------------------------------------
// Model_2886218023415: GAT/GraphConv graph stage -> BiLSTM+attn x2 -> FC
// Round 2: seq stage batches NS=4 samples per 256-thread block.
//   - xw projections kept in registers (acc[4][10]) — no LDS round trip
//   - Whh row (64 f) per thread, reused across 4 samples -> 256 FMA/barrier
//   - attention: Wa in 64-reg chunks, read once per block
// ---------------------------------------------------------------------------

#define NCH 7
#define SEQ 10
#define NN  10

// seq-kernel LDS geometry
#define RSTR 132     // row stride of [10][128] buffers (bank skew)
#define SSTR 1332    // per-sample stride (10*132 + 12)

// Fixed graph (20 directed edges), see reference _edges()
__constant__ int c_src[20] = {0,7,1,7,2,7,3,7,4,8,5,8,6,8,7,8,7,9,8,9};
__constant__ int c_dst[20] = {7,0,7,1,7,2,7,3,8,4,8,5,8,6,8,7,9,7,9,8};
__constant__ int c_in_start[11] = {0,2,4,6,8,10,12,14,21,27,30};
__constant__ int c_in_edge[30] = {1,20, 3,21, 5,22, 7,23, 9,24, 11,25, 13,26,
                                  0,2,4,6,15,17,27,
                                  8,10,12,14,19,28,
                                  16,18,29};
__constant__ int c_gin_start[11] = {0,1,2,3,4,5,6,7,13,18,20};
__constant__ int c_gin_src[20] = {7,7,7,7,8,8,8, 0,1,2,3,8,9, 4,5,6,7,9, 7,8};

__device__ __forceinline__ float fsig(float x){ return 1.f/(1.f + __expf(-x)); }
__device__ __forceinline__ float ftanh(float x){ return 1.f - 2.f/(__expf(2.f*x) + 1.f); }

// ---------------------------------------------------------------------------
// Kernel 1: graph stage. One wave (64 threads) per sample. Emits xseq [B,10,21].
// (unchanged from round 1 — known good; ~6% of runtime, revisit later)
// ---------------------------------------------------------------------------
__global__ __launch_bounds__(64) void graph_kernel(
    const float* __restrict__ M,
    const float* __restrict__ W1, const float* __restrict__ as1,
    const float* __restrict__ ad1, const float* __restrict__ b1,
    const float* __restrict__ W2, const float* __restrict__ as2,
    const float* __restrict__ ad2, const float* __restrict__ b2,
    const float* __restrict__ gWrel1, const float* __restrict__ gWroot1,
    const float* __restrict__ gb1,
    const float* __restrict__ gWrel2, const float* __restrict__ gWroot2,
    const float* __restrict__ gb2,
    float* __restrict__ xseq)
{
    const int b = blockIdx.x;
    const int tid = threadIdx.x;

    __shared__ float s_nf[10][10];
    __shared__ float s_xh[10][129];
    __shared__ float s_h[10][129];
    __shared__ float s_as[10][4], s_ad[10][4];
    __shared__ float s_al[30][4];
    __shared__ float s_xh2[10][10];
    __shared__ float s_as2[10], s_ad2[10];
    __shared__ float s_al2[30];
    __shared__ float s_mp[10][10];
    __shared__ float s_agg[10][10];
    __shared__ float s_g[10][33];
    __shared__ float s_gagg[10][33];
    __shared__ float s_bf[10][10];

    const float* Mb = M + (size_t)b * 70;
    for (int i = tid; i < 100; i += 64) {
        int n = i / 10, f = i - n * 10;
        s_nf[n][f] = (n < 7) ? Mb[n * 10 + f] : 0.f;
    }
    float wA[10], wB[10];
    #pragma unroll
    for (int f = 0; f < 10; f++) { wA[f] = W1[f*128 + tid]; wB[f] = W1[f*128 + tid + 64]; }
    __syncthreads();

    for (int n = 0; n < 10; n++) {
        float a0 = 0.f, a1 = 0.f;
        #pragma unroll
        for (int f = 0; f < 10; f++) { float x = s_nf[n][f]; a0 += x*wA[f]; a1 += x*wB[f]; }
        s_xh[n][tid] = a0; s_xh[n][tid + 64] = a1;
    }
    __syncthreads();
    if (tid < 40) {
        int n = tid >> 2, h = tid & 3;
        float va = 0.f, vd = 0.f;
        #pragma unroll
        for (int c = 0; c < 32; c++) {
            float x = s_xh[n][h*32 + c];
            va += x * as1[h*32 + c];
            vd += x * ad1[h*32 + c];
        }
        s_as[n][h] = va; s_ad[n][h] = vd;
    }
    __syncthreads();
    for (int i = tid; i < 120; i += 64) {
        int e = i >> 2, h = i & 3;
        int sn = (e < 20) ? c_src[e] : e - 20;
        int dn = (e < 20) ? c_dst[e] : e - 20;
        float v = s_as[sn][h] + s_ad[dn][h];
        s_al[e][h] = (v >= 0.f) ? v : 0.2f * v;
    }
    __syncthreads();
    if (tid < 40) {
        int n = tid >> 2, h = tid & 3;
        int st = c_in_start[n], en = c_in_start[n+1];
        float m = -1e30f;
        for (int j = st; j < en; j++) m = fmaxf(m, s_al[c_in_edge[j]][h]);
        float den = 0.f;
        for (int j = st; j < en; j++) den += __expf(s_al[c_in_edge[j]][h] - m);
        float inv = 1.f / den;
        for (int j = st; j < en; j++) {
            int e = c_in_edge[j];
            s_al[e][h] = __expf(s_al[e][h] - m) * inv;
        }
    }
    __syncthreads();
    for (int i = tid; i < 1280; i += 64) {
        int n = i >> 7, hc = i & 127, h = hc >> 5;
        int st = c_in_start[n], en = c_in_start[n+1];
        float o = b1[hc];
        for (int j = st; j < en; j++) {
            int e = c_in_edge[j];
            int sn = (e < 20) ? c_src[e] : e - 20;
            o += s_al[e][h] * s_xh[sn][hc];
        }
        s_h[n][hc] = fmaxf(o, 0.f);
    }
    __syncthreads();
    for (int i = tid; i < 100; i += 64) {
        int n = i / 10, c = i - (i / 10) * 10;
        float a = 0.f;
        #pragma unroll 16
        for (int f = 0; f < 128; f++) a += s_h[n][f] * W2[f*10 + c];
        s_xh2[n][c] = a;
    }
    __syncthreads();
    if (tid < 20) {
        int n = (tid < 10) ? tid : tid - 10;
        const float* av = (tid < 10) ? as2 : ad2;
        float v = 0.f;
        #pragma unroll
        for (int c = 0; c < 10; c++) v += s_xh2[n][c] * av[c];
        if (tid < 10) s_as2[n] = v; else s_ad2[n] = v;
    }
    __syncthreads();
    if (tid < 30) {
        int e = tid;
        int sn = (e < 20) ? c_src[e] : e - 20;
        int dn = (e < 20) ? c_dst[e] : e - 20;
        float v = s_as2[sn] + s_ad2[dn];
        s_al2[e] = (v >= 0.f) ? v : 0.2f * v;
    }
    __syncthreads();
    if (tid < 10) {
        int st = c_in_start[tid], en = c_in_start[tid+1];
        float m = -1e30f;
        for (int j = st; j < en; j++) m = fmaxf(m, s_al2[c_in_edge[j]]);
        float den = 0.f;
        for (int j = st; j < en; j++) den += __expf(s_al2[c_in_edge[j]] - m);
        float inv = 1.f / den;
        for (int j = st; j < en; j++) s_al2[c_in_edge[j]] = __expf(s_al2[c_in_edge[j]] - m) * inv;
    }
    __syncthreads();
    for (int i = tid; i < 100; i += 64) {
        int n = i / 10, c = i - (i / 10) * 10;
        int st = c_in_start[n], en = c_in_start[n+1];
        float o = b2[c];
        for (int j = st; j < en; j++) {
            int e = c_in_edge[j];
            int sn = (e < 20) ? c_src[e] : e - 20;
            o += s_al2[e] * s_xh2[sn][c];
        }
        s_mp[n][c] = o;
    }
    __syncthreads();
    for (int i = tid; i < 100; i += 64) {
        int n = i / 10, f = i - (i / 10) * 10;
        int st = c_gin_start[n], en = c_gin_start[n+1];
        float a = 0.f;
        for (int j = st; j < en; j++) a += s_nf[c_gin_src[j]][f];
        s_agg[n][f] = a;
    }
    __syncthreads();
    for (int i = tid; i < 320; i += 64) {
        int n = i >> 5, c = i & 31;
        float v = gb1[c];
        #pragma unroll
        for (int f = 0; f < 10; f++)
            v += s_agg[n][f] * gWrel1[f*32 + c] + s_nf[n][f] * gWroot1[f*32 + c];
        s_g[n][c] = fmaxf(v, 0.f);
    }
    __syncthreads();
    for (int i = tid; i < 320; i += 64) {
        int n = i >> 5, c = i & 31;
        int st = c_gin_start[n], en = c_gin_start[n+1];
        float a = 0.f;
        for (int j = st; j < en; j++) a += s_g[c_gin_src[j]][c];
        s_gagg[n][c] = a;
    }
    __syncthreads();
    for (int i = tid; i < 100; i += 64) {
        int n = i / 10, c = i - (i / 10) * 10;
        float v = gb2[c];
        #pragma unroll
        for (int f = 0; f < 32; f++)
            v += s_gagg[n][f] * gWrel2[f*10 + c] + s_g[n][f] * gWroot2[f*10 + c];
        s_bf[n][c] = v;
    }
    __syncthreads();
    float* xo = xseq + (size_t)b * 210;
    for (int i = tid; i < 210; i += 64) {
        int t = i / 21, k = i - (i / 21) * 21;
        float v;
        if (k < 7)       v = s_nf[k][t];
        else if (k < 14) v = s_mp[k - 7][t];
        else             v = s_bf[k - 14][t];
        xo[i] = v;
    }
}

// ---------------------------------------------------------------------------
// LSTM direction, 4 samples per 256-thread block. Thread j owns gate j for
// all 4 samples; xw kept in registers; Whh row in registers.
// ---------------------------------------------------------------------------
template<int IN, int ISS, int IRS>
__device__ __forceinline__ void lstm4(
    const float* __restrict__ Wih, const float* __restrict__ Whh,
    const float* __restrict__ bias, const float* __restrict__ s_in,
    float* __restrict__ s_O, int out_col, int reverse,
    float* __restrict__ s_h, float* __restrict__ s_g, int tid)
{
    // --- xw projections into registers: acc[s][ss], ss = step index ---
    float acc[4][10];
    {
        float bj = bias[tid];
        #pragma unroll
        for (int s = 0; s < 4; s++)
            #pragma unroll
            for (int ss = 0; ss < 10; ss++) acc[s][ss] = bj;
    }
    if constexpr (IN == 21) {
        const float* ir = Wih + (size_t)tid * 21;
        #pragma unroll
        for (int d4 = 0; d4 < 5; d4++) {
            float w0 = ir[d4*4], w1 = ir[d4*4+1], w2 = ir[d4*4+2], w3 = ir[d4*4+3];
            #pragma unroll
            for (int ss = 0; ss < 10; ss++) {
                int t = reverse ? 9 - ss : ss;
                #pragma unroll
                for (int s = 0; s < 4; s++) {
                    float4 xv = *(const float4*)(s_in + s*ISS + t*IRS + d4*4);
                    acc[s][ss] += w0*xv.x + w1*xv.y + w2*xv.z + w3*xv.w;
                }
            }
        }
        float w20 = ir[20];
        #pragma unroll
        for (int ss = 0; ss < 10; ss++) {
            int t = reverse ? 9 - ss : ss;
            #pragma unroll
            for (int s = 0; s < 4; s++)
                acc[s][ss] += w20 * s_in[s*ISS + t*IRS + 20];
        }
    } else {
        const float* ir = Wih + (size_t)tid * IN;
        for (int d = 0; d < IN; d += 4) {
            float4 wv = *(const float4*)(ir + d);
            #pragma unroll
            for (int ss = 0; ss < 10; ss++) {
                int t = reverse ? 9 - ss : ss;
                #pragma unroll
                for (int s = 0; s < 4; s++) {
                    float4 xv = *(const float4*)(s_in + s*ISS + t*IRS + d);
                    acc[s][ss] += wv.x*xv.x + wv.y*xv.y + wv.z*xv.z + wv.w*xv.w;
                }
            }
        }
    }

    // --- Whh row into registers ---
    float wh[64];
    {
        const float* wr = Whh + (size_t)tid * 64;
        #pragma unroll
        for (int k = 0; k < 64; k += 4) {
            float4 wv = *(const float4*)(wr + k);
            wh[k] = wv.x; wh[k+1] = wv.y; wh[k+2] = wv.z; wh[k+3] = wv.w;
        }
    }
    s_h[tid] = 0.f;          // s_h is [4][64] = 256 floats
    float c = 0.f;
    const int s_el = tid >> 6, i_el = tid & 63;
    __syncthreads();

    #pragma unroll 1
    for (int ss = 0; ss < 10; ss++) {
        int t = reverse ? 9 - ss : ss;
        float g0 = acc[0][ss], g1 = acc[1][ss], g2 = acc[2][ss], g3 = acc[3][ss];
        #pragma unroll
        for (int k = 0; k < 64; k += 4) {
            float4 h0 = *(const float4*)(s_h + k);
            float4 h1 = *(const float4*)(s_h + 64 + k);
            float4 h2 = *(const float4*)(s_h + 128 + k);
            float4 h3 = *(const float4*)(s_h + 192 + k);
            float wk0 = wh[k], wk1 = wh[k+1], wk2 = wh[k+2], wk3 = wh[k+3];
            g0 += wk0*h0.x + wk1*h0.y + wk2*h0.z + wk3*h0.w;
            g1 += wk0*h1.x + wk1*h1.y + wk2*h1.z + wk3*h1.w;
            g2 += wk0*h2.x + wk1*h2.y + wk2*h2.z + wk3*h2.w;
            g3 += wk0*h3.x + wk1*h3.y + wk2*h3.z + wk3*h3.w;
        }
        s_g[tid] = g0; s_g[256 + tid] = g1; s_g[512 + tid] = g2; s_g[768 + tid] = g3;
        __syncthreads();
        {
            const float* gb = s_g + s_el * 256;
            float ig = fsig(gb[i_el]);
            float fg = fsig(gb[64 + i_el]);
            float gg = ftanh(gb[128 + i_el]);
            float og = fsig(gb[192 + i_el]);
            c = fg * c + ig * gg;
            float hv = og * ftanh(c);
            s_h[tid] = hv;
            s_O[s_el*SSTR + t*RSTR + out_col + i_el] = hv;
        }
        __syncthreads();
    }
}

// ---------------------------------------------------------------------------
// Self-attention for 4 samples: out = softmax(tanh(O@Wa^T+ba) @ O^T) @ O
// Wa chunk (64 floats) per thread; partial k-halves combined via s_g.
// ---------------------------------------------------------------------------
__device__ __forceinline__ void attn4(
    const float* __restrict__ Wa, const float* __restrict__ ba,
    const float* __restrict__ O, float* __restrict__ out,
    float* __restrict__ Q, float* __restrict__ s_g, float* __restrict__ s_sc,
    int tid)
{
    const int f = tid & 127, half = tid >> 7;
    float wa[64];
    {
        const float* wr = Wa + (size_t)f * 128 + half * 64;
        #pragma unroll
        for (int k = 0; k < 64; k += 4) {
            float4 wv = *(const float4*)(wr + k);
            wa[k] = wv.x; wa[k+1] = wv.y; wa[k+2] = wv.z; wa[k+3] = wv.w;
        }
    }
    // Q phase: 40 (s,t) rows in groups of 4
    for (int gq = 0; gq < 10; gq++) {
        float p[4];
        #pragma unroll
        for (int pp = 0; pp < 4; pp++) {
            int pg = gq * 4 + pp;
            int s = pg / 10, t = pg - 10 * s;
            const float* orow = O + s*SSTR + t*RSTR + half*64;
            float a = 0.f;
            #pragma unroll
            for (int k = 0; k < 64; k += 4) {
                float4 ov = *(const float4*)(orow + k);
                a += wa[k]*ov.x + wa[k+1]*ov.y + wa[k+2]*ov.z + wa[k+3]*ov.w;
            }
            p[pp] = a;
        }
        __syncthreads();   // s_g free (prev group's readers done)
        #pragma unroll
        for (int pp = 0; pp < 4; pp++) s_g[half*512 + pp*128 + f] = p[pp];
        __syncthreads();
        #pragma unroll
        for (int r = 0; r < 2; r++) {
            int idx = r * 256 + tid;          // 0..511
            int pp = idx >> 7, ff = idx & 127;
            int pg = gq * 4 + pp;
            int s = pg / 10, t = pg - 10 * s;
            float q = ftanh(s_g[pp*128 + ff] + s_g[512 + pp*128 + ff] + ba[ff]);
            Q[s*SSTR + t*RSTR + ff] = q;
        }
    }
    __syncthreads();
    // scores: 400 dot-128
    if (tid < 200) {
        #pragma unroll
        for (int r = 0; r < 2; r++) {
            int idx = tid + r * 200;          // == s*100 + q*10 + k
            int s = idx / 100, rem = idx - s * 100;
            int q = rem / 10, k = rem - 10 * q;
            const float* qr = Q + s*SSTR + q*RSTR;
            const float* orow = O + s*SSTR + k*RSTR;
            float a = 0.f;
            #pragma unroll
            for (int kk = 0; kk < 128; kk += 4) {
                float4 qv = *(const float4*)(qr + kk);
                float4 ov = *(const float4*)(orow + kk);
                a += qv.x*ov.x + qv.y*ov.y + qv.z*ov.z + qv.w*ov.w;
            }
            s_sc[idx] = a;
        }
    }
    __syncthreads();
    // softmax over k for each of 40 (s,q) rows
    if (tid < 40) {
        float* row = s_sc + tid * 10;
        float m = -1e30f;
        #pragma unroll
        for (int k = 0; k < 10; k++) m = fmaxf(m, row[k]);
        float den = 0.f; float e[10];
        #pragma unroll
        for (int k = 0; k < 10; k++) { e[k] = __expf(row[k] - m); den += e[k]; }
        float inv = 1.f / den;
        #pragma unroll
        for (int k = 0; k < 10; k++) row[k] = e[k] * inv;
    }
    __syncthreads();
    // out = sc @ O : 1280 float4 outputs
    #pragma unroll
    for (int r = 0; r < 5; r++) {
        int idx = r * 256 + tid;              // 0..1279
        int s = idx / 320, rem = idx - s * 320;
        int t = rem >> 5, f4 = (rem & 31) * 4;
        const float* sc = s_sc + s * 100 + t * 10;
        float ax = 0.f, ay = 0.f, az = 0.f, aw = 0.f;
        #pragma unroll
        for (int k = 0; k < 10; k++) {
            float w = sc[k];
            float4 ov = *(const float4*)(O + s*SSTR + k*RSTR + f4);
            ax += w*ov.x; ay += w*ov.y; az += w*ov.z; aw += w*ov.w;
        }
        float4 res; res.x = ax; res.y = ay; res.z = az; res.w = aw;
        *(float4*)(out + s*SSTR + t*RSTR + f4) = res;
    }
    __syncthreads();
}

// ---------------------------------------------------------------------------
// Kernel 2: sequence stage, 4 samples per block.
// ---------------------------------------------------------------------------
__global__ __launch_bounds__(256) void seq_kernel(
    const float* __restrict__ xseq,
    const float* __restrict__ W1f_ih, const float* __restrict__ W1f_hh, const float* __restrict__ b1f,
    const float* __restrict__ W1b_ih, const float* __restrict__ W1b_hh, const float* __restrict__ b1b,
    const float* __restrict__ W2f_ih, const float* __restrict__ W2f_hh, const float* __restrict__ b2f,
    const float* __restrict__ W2b_ih, const float* __restrict__ W2b_hh, const float* __restrict__ b2b,
    const float* __restrict__ Wa1, const float* __restrict__ ba1,
    const float* __restrict__ Wa2, const float* __restrict__ ba2,
    float* __restrict__ xbar)
{
    const int b0 = blockIdx.x * 4;
    const int tid = threadIdx.x;

    __shared__ __align__(16) float sA[4 * SSTR];
    __shared__ __align__(16) float sB[4 * SSTR];
    __shared__ __align__(16) float sS[4 * SSTR];   // Q scratch
    __shared__ __align__(16) float s_x[4 * 240];   // layer1 input [s][t*24+d]
    __shared__ __align__(16) float s_g[1024];
    __shared__ __align__(16) float s_h[256];
    __shared__ float s_sc[400];

    for (int i = tid; i < 840; i += 256) {
        int s = i / 210, r = i - s * 210;
        int t = r / 21, k = r - t * 21;
        s_x[s*240 + t*24 + k] = xseq[(size_t)(b0 + s) * 210 + r];
    }
    __syncthreads();

    lstm4<21, 240, 24>(W1f_ih, W1f_hh, b1f, s_x, sA, 0,  0, s_h, s_g, tid);
    lstm4<21, 240, 24>(W1b_ih, W1b_hh, b1b, s_x, sA, 64, 1, s_h, s_g, tid);
    attn4(Wa1, ba1, sA, sB, sS, s_g, s_sc, tid);
    lstm4<128, SSTR, RSTR>(W2f_ih, W2f_hh, b2f, sB, sA, 0,  0, s_h, s_g, tid);
    lstm4<128, SSTR, RSTR>(W2b_ih, W2b_hh, b2b, sB, sA, 64, 1, s_h, s_g, tid);
    attn4(Wa2, ba2, sA, sB, sS, s_g, s_sc, tid);

    #pragma unroll
    for (int r = 0; r < 2; r++) {
        int idx = tid + r * 256;          // 0..511
        int s = idx >> 7, fo = idx & 127;
        float a = 0.f;
        #pragma unroll
        for (int t = 0; t < 10; t++) a += sB[s*SSTR + t*RSTR + fo];
        xbar[(size_t)(b0 + s) * 128 + fo] = a * 0.1f;
    }
}

// ---------------------------------------------------------------------------
// Kernel 3: FC  out[b][u] = xbar[b] . W[u] + bias[u]
// ---------------------------------------------------------------------------
__global__ __launch_bounds__(256) void fc_kernel(
    const float* __restrict__ xbar, const float* __restrict__ W,
    const float* __restrict__ fb, float* __restrict__ out, int B)
{
    __shared__ __align__(16) float s_xb[64 * RSTR];
    const int tid = threadIdx.x;
    const int b0 = blockIdx.y * 64;
    const int u0 = blockIdx.x * 64;

    for (int i = tid; i < 64 * 128; i += 256) {
        int s = i >> 7, k = i & 127;
        int bb = b0 + s;
        s_xb[s * RSTR + k] = (bb < B) ? xbar[(size_t)bb * 128 + k] : 0.f;
    }
    __syncthreads();

    const int tx = tid & 15, ty = tid >> 4;
    float acc[4][4] = {};
    for (int k = 0; k < 128; k += 4) {
        float4 wv[4], xv[4];
        #pragma unroll
        for (int j = 0; j < 4; j++) {
            int u = u0 + tx + 16 * j;
            int uc = (u < 1000) ? u : 999;
            wv[j] = *(const float4*)(W + (size_t)uc * 128 + k);
        }
        #pragma unroll
        for (int si = 0; si < 4; si++) {
            int s = ty + 16 * si;
            xv[si] = *(const float4*)(s_xb + s * RSTR + k);
        }
        #pragma unroll
        for (int j = 0; j < 4; j++)
            #pragma unroll
            for (int si = 0; si < 4; si++)
                acc[j][si] += wv[j].x*xv[si].x + wv[j].y*xv[si].y
                            + wv[j].z*xv[si].z + wv[j].w*xv[si].w;
    }
    #pragma unroll
    for (int j = 0; j < 4; j++) {
        int u = u0 + tx + 16 * j;
        if (u < 1000) {
            float bb = fb[u];
            #pragma unroll
            for (int si = 0; si < 4; si++) {
                int bsm = b0 + ty + 16 * si;
                if (bsm < B) out[(size_t)bsm * 1000 + u] = acc[j][si] + bb;
            }
        }
    }
}

// ---------------------------------------------------------------------------
extern "C" void kernel_launch(void* const* d_in, const int* in_sizes, int n_in,
                              void* d_out, int out_size, void* d_ws, size_t ws_size,
                              hipStream_t stream)
{
    const float* M       = (const float*)d_in[0];
    const float* ga1_W   = (const float*)d_in[1];
    const float* ga1_as  = (const float*)d_in[2];
    const float* ga1_ad  = (const float*)d_in[3];
    const float* ga1_b   = (const float*)d_in[4];
    const float* ga2_W   = (const float*)d_in[5];
    const float* ga2_as  = (const float*)d_in[6];
    const float* ga2_ad  = (const float*)d_in[7];
    const float* ga2_b   = (const float*)d_in[8];
    const float* gp1_Wrel  = (const float*)d_in[9];
    const float* gp1_Wroot = (const float*)d_in[10];
    const float* gp1_b     = (const float*)d_in[11];
    const float* gp2_Wrel  = (const float*)d_in[12];
    const float* gp2_Wroot = (const float*)d_in[13];
    const float* gp2_b     = (const float*)d_in[14];
    const float* l1f_Wih = (const float*)d_in[15];
    const float* l1f_Whh = (const float*)d_in[16];
    const float* l1f_b   = (const float*)d_in[17];
    const float* l1b_Wih = (const float*)d_in[18];
    const float* l1b_Whh = (const float*)d_in[19];
    const float* l1b_b   = (const float*)d_in[20];
    const float* l2f_Wih = (const float*)d_in[21];
    const float* l2f_Whh = (const float*)d_in[22];
    const float* l2f_b   = (const float*)d_in[23];
    const float* l2b_Wih = (const float*)d_in[24];
    const float* l2b_Whh = (const float*)d_in[25];
    const float* l2b_b   = (const float*)d_in[26];
    const float* a1_Wa   = (const float*)d_in[27];
    const float* a1_ba   = (const float*)d_in[28];
    const float* a2_Wa   = (const float*)d_in[29];
    const float* a2_ba   = (const float*)d_in[30];
    const float* fc_W    = (const float*)d_in[31];
    const float* fc_b    = (const float*)d_in[32];

    const int B = in_sizes[0] / 70;    // 32768

    float* xseq = (float*)d_ws;                                   // [B,10,21]
    float* xbar = (float*)((char*)d_ws + (size_t)B * 210 * 4);    // [B,128]

    graph_kernel<<<B, 64, 0, stream>>>(M,
        ga1_W, ga1_as, ga1_ad, ga1_b,
        ga2_W, ga2_as, ga2_ad, ga2_b,
        gp1_Wrel, gp1_Wroot, gp1_b,
        gp2_Wrel, gp2_Wroot, gp2_b,
        xseq);

    seq_kernel<<<B / 4, 256, 0, stream>>>(xseq,
        l1f_Wih, l1f_Whh, l1f_b,
        l1b_Wih, l1b_Whh, l1b_b,
        l2f_Wih, l2f_Whh, l2f_b,
        l2b_Wih, l2b_Whh, l2b_b,
        a1_Wa, a1_ba, a2_Wa, a2_ba,
        xbar);

    dim3 fgrid((1000 + 63) / 64, (B + 63) / 64);
    fc_kernel<<<fgrid, 256, 0, stream>>>(xbar, fc_W, fc_b, (float*)d_out, B);
}

// Round 3
// 3187.375 us; speedup vs baseline: 4.8326x; 2.0004x over previous
//
#include <hip/hip_runtime.h>
#include <hip/hip_bf16.h>
#include <cstdint>

// ---------------------------------------------------------------------------
// Model_2886218023415: GAT/GraphConv graph stage -> BiLSTM+attn x2 -> FC
// Round 3: seq stage = one wave per sample, ZERO barriers, f16 v_dot2 math.
//   - weights pre-packed to f16 pairs in d_ws by prep_kernel (runs every call)
//   - Whh rows live in 128 VGPRs as packed f16; recurrence is wave-synchronous
//   - __launch_bounds__(128,2) -> 2 waves/SIMD, 8 waves/CU
// ---------------------------------------------------------------------------

#define NCH 7
#define SEQ 10
#define NN  10

// Fixed graph (20 directed edges), see reference _edges()
__constant__ int c_src[20] = {0,7,1,7,2,7,3,7,4,8,5,8,6,8,7,8,7,9,8,9};
__constant__ int c_dst[20] = {7,0,7,1,7,2,7,3,8,4,8,5,8,6,8,7,9,7,9,8};
__constant__ int c_in_start[11] = {0,2,4,6,8,10,12,14,21,27,30};
__constant__ int c_in_edge[30] = {1,20, 3,21, 5,22, 7,23, 9,24, 11,25, 13,26,
                                  0,2,4,6,15,17,27,
                                  8,10,12,14,19,28,
                                  16,18,29};
__constant__ int c_gin_start[11] = {0,1,2,3,4,5,6,7,13,18,20};
__constant__ int c_gin_src[20] = {7,7,7,7,8,8,8, 0,1,2,3,8,9, 4,5,6,7,9, 7,8};

__device__ __forceinline__ float fsig(float x){ return 1.f/(1.f + __expf(-x)); }
__device__ __forceinline__ float ftanh(float x){ return 1.f - 2.f/(__expf(2.f*x) + 1.f); }

typedef _Float16 h2v __attribute__((ext_vector_type(2)));

#if defined(__has_builtin)
#if __has_builtin(__builtin_amdgcn_fdot2)
#define HAS_FDOT2 1
#endif
#endif

__device__ __forceinline__ float d2(uint32_t a, uint32_t b, float c){
#ifdef HAS_FDOT2
    return __builtin_amdgcn_fdot2(__builtin_bit_cast(h2v, a),
                                  __builtin_bit_cast(h2v, b), c, false);
#else
    union { uint32_t u; _Float16 h[2]; } ua, ub;
    ua.u = a; ub.u = b;
    return c + (float)ua.h[0]*(float)ub.h[0] + (float)ua.h[1]*(float)ub.h[1];
#endif
}

// ---------------- packed-weight layout in d_ws (u32 units) -----------------
#define OFF_W1F 0        // [256][12]  (l1f_Wih, d padded 21->24)
#define OFF_W1B 3072
#define OFF_H1F 6144     // [256][32]  (l1f_Whh)
#define OFF_H1B 14336
#define OFF_W2F 22528    // [256][64]  (l2f_Wih)
#define OFF_W2B 38912
#define OFF_H2F 55296    // [256][32]
#define OFF_H2B 63488
#define OFF_WA1 71680    // [128][64]
#define OFF_WA2 79872
#define WPK_TOTAL 88064

__global__ __launch_bounds__(256) void prep_kernel(
    const float* __restrict__ w1f, const float* __restrict__ w1b,
    const float* __restrict__ h1f, const float* __restrict__ h1b,
    const float* __restrict__ w2f, const float* __restrict__ w2b,
    const float* __restrict__ h2f, const float* __restrict__ h2b,
    const float* __restrict__ wa1, const float* __restrict__ wa2,
    uint32_t* __restrict__ wpk)
{
    int i = blockIdx.x * 256 + threadIdx.x;
    if (i >= WPK_TOTAL) return;
    const float* src; int K, P, row, p;
    if (i < 6144) {
        int j = i; src = w1f; if (j >= 3072) { src = w1b; j -= 3072; }
        K = 21; P = 12; row = j / P; p = j - row * P;
    } else if (i < 22528) {
        int j = i - 6144; src = h1f; if (j >= 8192) { src = h1b; j -= 8192; }
        K = 64; P = 32; row = j / P; p = j - row * P;
    } else if (i < 55296) {
        int j = i - 22528; src = w2f; if (j >= 16384) { src = w2b; j -= 16384; }
        K = 128; P = 64; row = j / P; p = j - row * P;
    } else if (i < 71680) {
        int j = i - 55296; src = h2f; if (j >= 8192) { src = h2b; j -= 8192; }
        K = 64; P = 32; row = j / P; p = j - row * P;
    } else {
        int j = i - 71680; src = wa1; if (j >= 8192) { src = wa2; j -= 8192; }
        K = 128; P = 64; row = j / P; p = j - row * P;
    }
    int d0 = 2 * p;
    float v0 = (d0     < K) ? src[row * K + d0]     : 0.f;
    float v1 = (d0 + 1 < K) ? src[row * K + d0 + 1] : 0.f;
    union { _Float16 h[2]; uint32_t u; } x;
    x.h[0] = (_Float16)v0; x.h[1] = (_Float16)v1;
    wpk[i] = x.u;
}

// ---------------------------------------------------------------------------
// Kernel 1: graph stage (unchanged from round 2 — known good).
// ---------------------------------------------------------------------------
__global__ __launch_bounds__(64) void graph_kernel(
    const float* __restrict__ M,
    const float* __restrict__ W1, const float* __restrict__ as1,
    const float* __restrict__ ad1, const float* __restrict__ b1,
    const float* __restrict__ W2, const float* __restrict__ as2,
    const float* __restrict__ ad2, const float* __restrict__ b2,
    const float* __restrict__ gWrel1, const float* __restrict__ gWroot1,
    const float* __restrict__ gb1,
    const float* __restrict__ gWrel2, const float* __restrict__ gWroot2,
    const float* __restrict__ gb2,
    float* __restrict__ xseq)
{
    const int b = blockIdx.x;
    const int tid = threadIdx.x;

    __shared__ float s_nf[10][10];
    __shared__ float s_xh[10][129];
    __shared__ float s_h[10][129];
    __shared__ float s_as[10][4], s_ad[10][4];
    __shared__ float s_al[30][4];
    __shared__ float s_xh2[10][10];
    __shared__ float s_as2[10], s_ad2[10];
    __shared__ float s_al2[30];
    __shared__ float s_mp[10][10];
    __shared__ float s_agg[10][10];
    __shared__ float s_g[10][33];
    __shared__ float s_gagg[10][33];
    __shared__ float s_bf[10][10];

    const float* Mb = M + (size_t)b * 70;
    for (int i = tid; i < 100; i += 64) {
        int n = i / 10, f = i - n * 10;
        s_nf[n][f] = (n < 7) ? Mb[n * 10 + f] : 0.f;
    }
    float wA[10], wB[10];
    #pragma unroll
    for (int f = 0; f < 10; f++) { wA[f] = W1[f*128 + tid]; wB[f] = W1[f*128 + tid + 64]; }
    __syncthreads();

    for (int n = 0; n < 10; n++) {
        float a0 = 0.f, a1 = 0.f;
        #pragma unroll
        for (int f = 0; f < 10; f++) { float x = s_nf[n][f]; a0 += x*wA[f]; a1 += x*wB[f]; }
        s_xh[n][tid] = a0; s_xh[n][tid + 64] = a1;
    }
    __syncthreads();
    if (tid < 40) {
        int n = tid >> 2, h = tid & 3;
        float va = 0.f, vd = 0.f;
        #pragma unroll
        for (int c = 0; c < 32; c++) {
            float x = s_xh[n][h*32 + c];
            va += x * as1[h*32 + c];
            vd += x * ad1[h*32 + c];
        }
        s_as[n][h] = va; s_ad[n][h] = vd;
    }
    __syncthreads();
    for (int i = tid; i < 120; i += 64) {
        int e = i >> 2, h = i & 3;
        int sn = (e < 20) ? c_src[e] : e - 20;
        int dn = (e < 20) ? c_dst[e] : e - 20;
        float v = s_as[sn][h] + s_ad[dn][h];
        s_al[e][h] = (v >= 0.f) ? v : 0.2f * v;
    }
    __syncthreads();
    if (tid < 40) {
        int n = tid >> 2, h = tid & 3;
        int st = c_in_start[n], en = c_in_start[n+1];
        float m = -1e30f;
        for (int j = st; j < en; j++) m = fmaxf(m, s_al[c_in_edge[j]][h]);
        float den = 0.f;
        for (int j = st; j < en; j++) den += __expf(s_al[c_in_edge[j]][h] - m);
        float inv = 1.f / den;
        for (int j = st; j < en; j++) {
            int e = c_in_edge[j];
            s_al[e][h] = __expf(s_al[e][h] - m) * inv;
        }
    }
    __syncthreads();
    for (int i = tid; i < 1280; i += 64) {
        int n = i >> 7, hc = i & 127, h = hc >> 5;
        int st = c_in_start[n], en = c_in_start[n+1];
        float o = b1[hc];
        for (int j = st; j < en; j++) {
            int e = c_in_edge[j];
            int sn = (e < 20) ? c_src[e] : e - 20;
            o += s_al[e][h] * s_xh[sn][hc];
        }
        s_h[n][hc] = fmaxf(o, 0.f);
    }
    __syncthreads();
    for (int i = tid; i < 100; i += 64) {
        int n = i / 10, c = i - (i / 10) * 10;
        float a = 0.f;
        #pragma unroll 16
        for (int f = 0; f < 128; f++) a += s_h[n][f] * W2[f*10 + c];
        s_xh2[n][c] = a;
    }
    __syncthreads();
    if (tid < 20) {
        int n = (tid < 10) ? tid : tid - 10;
        const float* av = (tid < 10) ? as2 : ad2;
        float v = 0.f;
        #pragma unroll
        for (int c = 0; c < 10; c++) v += s_xh2[n][c] * av[c];
        if (tid < 10) s_as2[n] = v; else s_ad2[n] = v;
    }
    __syncthreads();
    if (tid < 30) {
        int e = tid;
        int sn = (e < 20) ? c_src[e] : e - 20;
        int dn = (e < 20) ? c_dst[e] : e - 20;
        float v = s_as2[sn] + s_ad2[dn];
        s_al2[e] = (v >= 0.f) ? v : 0.2f * v;
    }
    __syncthreads();
    if (tid < 10) {
        int st = c_in_start[tid], en = c_in_start[tid+1];
        float m = -1e30f;
        for (int j = st; j < en; j++) m = fmaxf(m, s_al2[c_in_edge[j]]);
        float den = 0.f;
        for (int j = st; j < en; j++) den += __expf(s_al2[c_in_edge[j]] - m);
        float inv = 1.f / den;
        for (int j = st; j < en; j++) s_al2[c_in_edge[j]] = __expf(s_al2[c_in_edge[j]] - m) * inv;
    }
    __syncthreads();
    for (int i = tid; i < 100; i += 64) {
        int n = i / 10, c = i - (i / 10) * 10;
        int st = c_in_start[n], en = c_in_start[n+1];
        float o = b2[c];
        for (int j = st; j < en; j++) {
            int e = c_in_edge[j];
            int sn = (e < 20) ? c_src[e] : e - 20;
            o += s_al2[e] * s_xh2[sn][c];
        }
        s_mp[n][c] = o;
    }
    __syncthreads();
    for (int i = tid; i < 100; i += 64) {
        int n = i / 10, f = i - (i / 10) * 10;
        int st = c_gin_start[n], en = c_gin_start[n+1];
        float a = 0.f;
        for (int j = st; j < en; j++) a += s_nf[c_gin_src[j]][f];
        s_agg[n][f] = a;
    }
    __syncthreads();
    for (int i = tid; i < 320; i += 64) {
        int n = i >> 5, c = i & 31;
        float v = gb1[c];
        #pragma unroll
        for (int f = 0; f < 10; f++)
            v += s_agg[n][f] * gWrel1[f*32 + c] + s_nf[n][f] * gWroot1[f*32 + c];
        s_g[n][c] = fmaxf(v, 0.f);
    }
    __syncthreads();
    for (int i = tid; i < 320; i += 64) {
        int n = i >> 5, c = i & 31;
        int st = c_gin_start[n], en = c_gin_start[n+1];
        float a = 0.f;
        for (int j = st; j < en; j++) a += s_g[c_gin_src[j]][c];
        s_gagg[n][c] = a;
    }
    __syncthreads();
    for (int i = tid; i < 100; i += 64) {
        int n = i / 10, c = i - (i / 10) * 10;
        float v = gb2[c];
        #pragma unroll
        for (int f = 0; f < 32; f++)
            v += s_gagg[n][f] * gWrel2[f*10 + c] + s_g[n][f] * gWroot2[f*10 + c];
        s_bf[n][c] = v;
    }
    __syncthreads();
    float* xo = xseq + (size_t)b * 210;
    for (int i = tid; i < 210; i += 64) {
        int t = i / 21, k = i - (i / 21) * 21;
        float v;
        if (k < 7)       v = s_nf[k][t];
        else if (k < 14) v = s_mp[k - 7][t];
        else             v = s_bf[k - 14][t];
        xo[i] = v;
    }
}

// ---------------------------------------------------------------------------
// Per-wave LDS layout (u32 units), one region per wave:
//   X2  [10][12] packed f16 input            @ 0    (120)
//   H2  [32]     packed f16 hidden state     @ 120  (32)
//   SC  [100]    f32 attn scores             @ 152  (100)
//   OF  [10][132] f32 bilstm output          @ 252  (1320)
//   O2  [10][68] packed f16 bilstm output    @ 1572 (680)
//   Q2  [10][68] packed f16 attn Q           @ 2252 (680)
//   A2  [10][68] packed f16 attn out         @ 2932 (680)
#define X2O 0
#define H2O 120
#define SCO 152
#define OFO 252
#define O2O 1572
#define Q2O 2252
#define A2O 2932
#define WSZ 3616

// One LSTM direction for one sample (one wave). Lane l owns hidden unit l:
// gate rows {l, 64+l, 128+l, 192+l}. Whh packed rows in 128 VGPRs.
template<int REV, int L1>
__device__ __forceinline__ void lstm_pass(
    const uint32_t* __restrict__ wih, const uint32_t* __restrict__ whh,
    const float* __restrict__ bias, uint32_t* __restrict__ L,
    float* __restrict__ Of, int l, int col)
{
    float acc[4][10];
    #pragma unroll
    for (int g = 0; g < 4; g++) {
        float bj = bias[g * 64 + l];
        #pragma unroll
        for (int t = 0; t < 10; t++) acc[g][t] = bj;
    }
    // ---- xw projections (streamed weights, broadcast LDS input) ----
    if constexpr (L1) {
        #pragma unroll
        for (int c = 0; c < 3; c++) {
            uint4 w[4];
            #pragma unroll
            for (int g = 0; g < 4; g++)
                w[g] = *(const uint4*)(wih + (g * 64 + l) * 12 + c * 4);
            #pragma unroll
            for (int t = 0; t < 10; t++) {
                uint4 x = *(const uint4*)(L + X2O + t * 12 + c * 4);
                #pragma unroll
                for (int g = 0; g < 4; g++)
                    acc[g][t] = d2(w[g].w, x.w, d2(w[g].z, x.z,
                                d2(w[g].y, x.y, d2(w[g].x, x.x, acc[g][t]))));
            }
        }
    } else {
        #pragma unroll 4
        for (int c = 0; c < 16; c++) {
            uint4 w[4];
            #pragma unroll
            for (int g = 0; g < 4; g++)
                w[g] = *(const uint4*)(wih + (g * 64 + l) * 64 + c * 4);
            #pragma unroll
            for (int t = 0; t < 10; t++) {
                uint4 x = *(const uint4*)(L + A2O + t * 68 + c * 4);
                #pragma unroll
                for (int g = 0; g < 4; g++)
                    acc[g][t] = d2(w[g].w, x.w, d2(w[g].z, x.z,
                                d2(w[g].y, x.y, d2(w[g].x, x.x, acc[g][t]))));
            }
        }
    }
    // ---- Whh rows into registers (4 x 32 u32 = 128 VGPR) ----
    uint4 wh[4][8];
    #pragma unroll
    for (int g = 0; g < 4; g++)
        #pragma unroll
        for (int cc = 0; cc < 8; cc++)
            wh[g][cc] = *(const uint4*)(whh + (g * 64 + l) * 32 + cc * 4);

    _Float16* h2h = (_Float16*)(L + H2O);
    h2h[l] = (_Float16)0.f;
    float cs = 0.f;
    // ---- recurrence: wave-synchronous, no barriers ----
    #pragma unroll
    for (int ss = 0; ss < 10; ss++) {
        const int t = REV ? 9 - ss : ss;
        uint4 h[8];
        #pragma unroll
        for (int cc = 0; cc < 8; cc++)
            h[cc] = *(const uint4*)(L + H2O + cc * 4);
        float gv[4];
        #pragma unroll
        for (int g = 0; g < 4; g++) {
            float p0 = acc[g][t], p1 = 0.f;
            #pragma unroll
            for (int cc = 0; cc < 4; cc++) {
                p0 = d2(wh[g][cc].w, h[cc].w, d2(wh[g][cc].z, h[cc].z,
                     d2(wh[g][cc].y, h[cc].y, d2(wh[g][cc].x, h[cc].x, p0))));
                p1 = d2(wh[g][cc+4].w, h[cc+4].w, d2(wh[g][cc+4].z, h[cc+4].z,
                     d2(wh[g][cc+4].y, h[cc+4].y, d2(wh[g][cc+4].x, h[cc+4].x, p1))));
            }
            gv[g] = p0 + p1;
        }
        float ig = fsig(gv[0]), fg = fsig(gv[1]);
        float gg = ftanh(gv[2]), og = fsig(gv[3]);
        cs = fg * cs + ig * gg;
        float hv = og * ftanh(cs);
        h2h[l] = (_Float16)hv;
        Of[t * 132 + col + l] = hv;
        ((_Float16*)(L + O2O))[t * 136 + col + l] = (_Float16)hv;
    }
}

// Self-attention for one sample (one wave): out = softmax(tanh(O Wa^T + ba) O^T) O
template<int FINAL>
__device__ __forceinline__ void attn_pass(
    const uint32_t* __restrict__ wa, const float* __restrict__ ba,
    uint32_t* __restrict__ L, float* __restrict__ Of, int l,
    float* __restrict__ outg)
{
    float qa0[10], qa1[10];
    {
        float b0 = ba[l], b1 = ba[64 + l];
        #pragma unroll
        for (int t = 0; t < 10; t++) { qa0[t] = b0; qa1[t] = b1; }
    }
    #pragma unroll 4
    for (int c = 0; c < 16; c++) {
        uint4 w0 = *(const uint4*)(wa + l * 64 + c * 4);
        uint4 w1 = *(const uint4*)(wa + (64 + l) * 64 + c * 4);
        #pragma unroll
        for (int t = 0; t < 10; t++) {
            uint4 o = *(const uint4*)(L + O2O + t * 68 + c * 4);
            qa0[t] = d2(w0.w, o.w, d2(w0.z, o.z, d2(w0.y, o.y, d2(w0.x, o.x, qa0[t]))));
            qa1[t] = d2(w1.w, o.w, d2(w1.z, o.z, d2(w1.y, o.y, d2(w1.x, o.x, qa1[t]))));
        }
    }
    _Float16* q2h = (_Float16*)(L + Q2O);
    #pragma unroll
    for (int t = 0; t < 10; t++) {
        q2h[t * 136 + l]      = (_Float16)ftanh(qa0[t]);
        q2h[t * 136 + 64 + l] = (_Float16)ftanh(qa1[t]);
    }
    float* sc = (float*)(L + SCO);
    #pragma unroll
    for (int r = 0; r < 2; r++) {
        int idx = l + r * 64;
        if (idx < 100) {
            int q = idx / 10, k = idx - 10 * q;
            float s = 0.f;
            #pragma unroll
            for (int m = 0; m < 16; m++) {
                uint4 a = *(const uint4*)(L + Q2O + q * 68 + m * 4);
                uint4 b = *(const uint4*)(L + O2O + k * 68 + m * 4);
                s = d2(a.w, b.w, d2(a.z, b.z, d2(a.y, b.y, d2(a.x, b.x, s))));
            }
            sc[idx] = s;
        }
    }
    if (l < 10) {
        float m = -1e30f;
        #pragma unroll
        for (int k = 0; k < 10; k++) m = fmaxf(m, sc[l * 10 + k]);
        float den = 0.f, e[10];
        #pragma unroll
        for (int k = 0; k < 10; k++) { e[k] = __expf(sc[l * 10 + k] - m); den += e[k]; }
        float inv = 1.f / den;
        #pragma unroll
        for (int k = 0; k < 10; k++) sc[l * 10 + k] = e[k] * inv;
    }
    float pa0[10], pa1[10];
    #pragma unroll
    for (int t = 0; t < 10; t++) { pa0[t] = 0.f; pa1[t] = 0.f; }
    #pragma unroll
    for (int k = 0; k < 10; k++) {
        float o0 = Of[k * 132 + l], o1 = Of[k * 132 + 64 + l];
        #pragma unroll
        for (int t = 0; t < 10; t++) {
            float s = sc[t * 10 + k];
            pa0[t] += s * o0; pa1[t] += s * o1;
        }
    }
    if constexpr (FINAL) {
        float s0 = 0.f, s1 = 0.f;
        #pragma unroll
        for (int t = 0; t < 10; t++) { s0 += pa0[t]; s1 += pa1[t]; }
        outg[l] = s0 * 0.1f; outg[64 + l] = s1 * 0.1f;
    } else {
        _Float16* a2h = (_Float16*)(L + A2O);
        #pragma unroll
        for (int t = 0; t < 10; t++) {
            a2h[t * 136 + l]      = (_Float16)pa0[t];
            a2h[t * 136 + 64 + l] = (_Float16)pa1[t];
        }
    }
}

// ---------------------------------------------------------------------------
// Kernel 2: sequence stage — 2 waves per block, 1 sample per wave, no barriers.
// ---------------------------------------------------------------------------
__global__ __launch_bounds__(128, 2) void seq_kernel(
    const float* __restrict__ xseq, const uint32_t* __restrict__ wpk,
    const float* __restrict__ b1f, const float* __restrict__ b1b,
    const float* __restrict__ b2f, const float* __restrict__ b2b,
    const float* __restrict__ ba1, const float* __restrict__ ba2,
    float* __restrict__ xbar)
{
    __shared__ __align__(16) uint32_t lds[2 * WSZ];
    const int wid = threadIdx.x >> 6, l = threadIdx.x & 63;
    const int b = blockIdx.x * 2 + wid;
    uint32_t* L = lds + wid * WSZ;
    float* Of = (float*)(L + OFO);

    // load + pack input [10][21] -> f16 pairs [10][12] (pad with 0)
    const float* xs = xseq + (size_t)b * 210;
    for (int i = l; i < 120; i += 64) {
        int t = i / 12, pr = i - 12 * t;
        int d0 = 2 * pr;
        float v0 = (d0     < 21) ? xs[t * 21 + d0]     : 0.f;
        float v1 = (d0 + 1 < 21) ? xs[t * 21 + d0 + 1] : 0.f;
        union { _Float16 h[2]; uint32_t u; } p;
        p.h[0] = (_Float16)v0; p.h[1] = (_Float16)v1;
        L[X2O + i] = p.u;
    }

    lstm_pass<0,1>(wpk + OFF_W1F, wpk + OFF_H1F, b1f, L, Of, l, 0);
    lstm_pass<1,1>(wpk + OFF_W1B, wpk + OFF_H1B, b1b, L, Of, l, 64);
    attn_pass<0>(wpk + OFF_WA1, ba1, L, Of, l, nullptr);
    lstm_pass<0,0>(wpk + OFF_W2F, wpk + OFF_H2F, b2f, L, Of, l, 0);
    lstm_pass<1,0>(wpk + OFF_W2B, wpk + OFF_H2B, b2b, L, Of, l, 64);
    attn_pass<1>(wpk + OFF_WA2, ba2, L, Of, l, xbar + (size_t)b * 128);
}

// ---------------------------------------------------------------------------
// Kernel 3: FC  out[b][u] = xbar[b] . W[u] + bias[u]
// ---------------------------------------------------------------------------
__global__ __launch_bounds__(256) void fc_kernel(
    const float* __restrict__ xbar, const float* __restrict__ W,
    const float* __restrict__ fb, float* __restrict__ out, int B)
{
    __shared__ __align__(16) float s_xb[64 * 132];
    const int tid = threadIdx.x;
    const int b0 = blockIdx.y * 64;
    const int u0 = blockIdx.x * 64;

    for (int i = tid; i < 64 * 128; i += 256) {
        int s = i >> 7, k = i & 127;
        int bb = b0 + s;
        s_xb[s * 132 + k] = (bb < B) ? xbar[(size_t)bb * 128 + k] : 0.f;
    }
    __syncthreads();

    const int tx = tid & 15, ty = tid >> 4;
    float acc[4][4] = {};
    for (int k = 0; k < 128; k += 4) {
        float4 wv[4], xv[4];
        #pragma unroll
        for (int j = 0; j < 4; j++) {
            int u = u0 + tx + 16 * j;
            int uc = (u < 1000) ? u : 999;
            wv[j] = *(const float4*)(W + (size_t)uc * 128 + k);
        }
        #pragma unroll
        for (int si = 0; si < 4; si++) {
            int s = ty + 16 * si;
            xv[si] = *(const float4*)(s_xb + s * 132 + k);
        }
        #pragma unroll
        for (int j = 0; j < 4; j++)
            #pragma unroll
            for (int si = 0; si < 4; si++)
                acc[j][si] += wv[j].x*xv[si].x + wv[j].y*xv[si].y
                            + wv[j].z*xv[si].z + wv[j].w*xv[si].w;
    }
    #pragma unroll
    for (int j = 0; j < 4; j++) {
        int u = u0 + tx + 16 * j;
        if (u < 1000) {
            float bb = fb[u];
            #pragma unroll
            for (int si = 0; si < 4; si++) {
                int bsm = b0 + ty + 16 * si;
                if (bsm < B) out[(size_t)bsm * 1000 + u] = acc[j][si] + bb;
            }
        }
    }
}

// ---------------------------------------------------------------------------
extern "C" void kernel_launch(void* const* d_in, const int* in_sizes, int n_in,
                              void* d_out, int out_size, void* d_ws, size_t ws_size,
                              hipStream_t stream)
{
    const float* M       = (const float*)d_in[0];
    const float* ga1_W   = (const float*)d_in[1];
    const float* ga1_as  = (const float*)d_in[2];
    const float* ga1_ad  = (const float*)d_in[3];
    const float* ga1_b   = (const float*)d_in[4];
    const float* ga2_W   = (const float*)d_in[5];
    const float* ga2_as  = (const float*)d_in[6];
    const float* ga2_ad  = (const float*)d_in[7];
    const float* ga2_b   = (const float*)d_in[8];
    const float* gp1_Wrel  = (const float*)d_in[9];
    const float* gp1_Wroot = (const float*)d_in[10];
    const float* gp1_b     = (const float*)d_in[11];
    const float* gp2_Wrel  = (const float*)d_in[12];
    const float* gp2_Wroot = (const float*)d_in[13];
    const float* gp2_b     = (const float*)d_in[14];
    const float* l1f_Wih = (const float*)d_in[15];
    const float* l1f_Whh = (const float*)d_in[16];
    const float* l1f_b   = (const float*)d_in[17];
    const float* l1b_Wih = (const float*)d_in[18];
    const float* l1b_Whh = (const float*)d_in[19];
    const float* l1b_b   = (const float*)d_in[20];
    const float* l2f_Wih = (const float*)d_in[21];
    const float* l2f_Whh = (const float*)d_in[22];
    const float* l2f_b   = (const float*)d_in[23];
    const float* l2b_Wih = (const float*)d_in[24];
    const float* l2b_Whh = (const float*)d_in[25];
    const float* l2b_b   = (const float*)d_in[26];
    const float* a1_Wa   = (const float*)d_in[27];
    const float* a1_ba   = (const float*)d_in[28];
    const float* a2_Wa   = (const float*)d_in[29];
    const float* a2_ba   = (const float*)d_in[30];
    const float* fc_W    = (const float*)d_in[31];
    const float* fc_b    = (const float*)d_in[32];

    const int B = in_sizes[0] / 70;    // 32768

    float* xseq = (float*)d_ws;                                       // [B,10,21]
    float* xbar = (float*)((char*)d_ws + (size_t)B * 210 * 4);        // [B,128]
    uint32_t* wpk = (uint32_t*)((char*)d_ws + (size_t)B * 210 * 4
                                            + (size_t)B * 128 * 4);   // packed f16 weights

    prep_kernel<<<(WPK_TOTAL + 255) / 256, 256, 0, stream>>>(
        l1f_Wih, l1b_Wih, l1f_Whh, l1b_Whh,
        l2f_Wih, l2b_Wih, l2f_Whh, l2b_Whh,
        a1_Wa, a2_Wa, wpk);

    graph_kernel<<<B, 64, 0, stream>>>(M,
        ga1_W, ga1_as, ga1_ad, ga1_b,
        ga2_W, ga2_as, ga2_ad, ga2_b,
        gp1_Wrel, gp1_Wroot, gp1_b,
        gp2_Wrel, gp2_Wroot, gp2_b,
        xseq);

    seq_kernel<<<B / 2, 128, 0, stream>>>(xseq, wpk,
        l1f_b, l1b_b, l2f_b, l2b_b, a1_ba, a2_ba, xbar);

    dim3 fgrid((1000 + 63) / 64, (B + 63) / 64);
    fc_kernel<<<fgrid, 256, 0, stream>>>(xbar, fc_W, fc_b, (float*)d_out, B);
}